// Round 1
// 158.859 us; speedup vs baseline: 6.7248x; 6.7248x over previous
//
#include <hip/hip_runtime.h>
#include <math.h>

// Problem constants
#define B_ 16
#define L_ 512
#define F_ 384
#define H_ 384
#define K_ 3
#define MAX_OUT_ 4096
#define EPS_ 1e-5f

#define M_TOTAL (B_ * L_)   // 8192 gemm rows
#define KDIM (K_ * F_)      // 1152 gemm K
#define NW (H_ * F_ * K_)   // 442368 weight elems per conv
#define NXE (B_ * L_ * F_)  // 3145728 activation elems

typedef __attribute__((ext_vector_type(8))) short bf16x8;   // 8 bf16 = 4 VGPR
typedef __attribute__((ext_vector_type(4))) float f32x4;

// ---------------------------------------------------------------------------
// bf16 split helpers: v = hi + lo with RNE rounding (3-term product error ~2^-17)
// ---------------------------------------------------------------------------
__device__ inline unsigned short bf16_rne(float v) {
    unsigned int u = __float_as_uint(v);
    unsigned int r = (u + 0x7fffu + ((u >> 16) & 1u)) >> 16;
    return (unsigned short)r;
}
__device__ inline void bf16_split(float v, unsigned short& hi, unsigned short& lo) {
    hi = bf16_rne(v);
    float hf = __uint_as_float(((unsigned int)hi) << 16);
    lo = bf16_rne(v - hf);
}

// ---------------------------------------------------------------------------
// Kernel 1: per-batch cumsum of target + searchsorted index table (unchanged).
// ---------------------------------------------------------------------------
__global__ void k_scan_idx(const int* __restrict__ target, int* __restrict__ idx) {
    __shared__ int e[L_];
    const int b = blockIdx.x;
    const int tid = threadIdx.x;   // blockDim = 512 = L_
    e[tid] = target[b * L_ + tid];
    __syncthreads();
    for (int off = 1; off < L_; off <<= 1) {
        int add = (tid >= off) ? e[tid - off] : 0;
        __syncthreads();
        e[tid] += add;
        __syncthreads();
    }
    const int total = e[L_ - 1];
    for (int t = tid; t < MAX_OUT_; t += L_) {
        int lo = 0, hi = L_;
        while (lo < hi) {
            int m = (lo + hi) >> 1;
            if (e[m] <= t) lo = m + 1; else hi = m;
        }
        int v = (t < total) ? min(lo, L_ - 1) : -1;
        idx[b * MAX_OUT_ + t] = v;
    }
}

// ---------------------------------------------------------------------------
// Kernel 2: prep — split input x into bf16 hi/lo planes; transpose+split both
// conv weights to [h][tap*384+f] hi/lo planes.
// ---------------------------------------------------------------------------
__global__ void k_prep(const float* __restrict__ x,
                       const float* __restrict__ w1, const float* __restrict__ w2,
                       unsigned short* __restrict__ xh, unsigned short* __restrict__ xl,
                       unsigned short* __restrict__ w1h, unsigned short* __restrict__ w1l,
                       unsigned short* __restrict__ w2h, unsigned short* __restrict__ w2l) {
    const int NX4 = NXE / 4;
    const int total = NX4 + 2 * NW;
    for (int i = blockIdx.x * blockDim.x + threadIdx.x; i < total;
         i += gridDim.x * blockDim.x) {
        if (i < NX4) {
            float4 v = ((const float4*)x)[i];
            ushort4 hv, lv;
            bf16_split(v.x, hv.x, lv.x);
            bf16_split(v.y, hv.y, lv.y);
            bf16_split(v.z, hv.z, lv.z);
            bf16_split(v.w, hv.w, lv.w);
            ((ushort4*)xh)[i] = hv;
            ((ushort4*)xl)[i] = lv;
        } else {
            int j = i - NX4;
            const float* w = (j < NW) ? w1 : w2;
            unsigned short* ohp = (j < NW) ? w1h : w2h;
            unsigned short* olp = (j < NW) ? w1l : w2l;
            int o = (j < NW) ? j : j - NW;
            int h = o / KDIM;
            int rem = o - h * KDIM;
            int k = rem / F_;
            int f = rem - k * F_;
            unsigned short hi, lo;
            bf16_split(w[(h * F_ + f) * K_ + k], hi, lo);
            ohp[o] = hi;
            olp[o] = lo;
        }
    }
}

// ---------------------------------------------------------------------------
// Kernel 3: conv-as-GEMM via split-bf16 MFMA (3 terms: hh + hl + lh).
// Block = 256 thr (4 waves), tile 64 rows x 64 channels, split-K: each wave
// owns K-slice of 288 (of 1152 = 3 taps x 384). A/B fragments loaded directly
// from L2 (pre-split planes), LDS only for the 48KB split-K reduction.
// A[row][k=tap*384+f] = x[b][l+tap-1][f] (0 if out of range), B[k][h] = wt[h][k].
// ---------------------------------------------------------------------------
__global__ __launch_bounds__(256, 3) void k_gemm(
        const unsigned short* __restrict__ Ahi,
        const unsigned short* __restrict__ Alo,
        const unsigned short* __restrict__ Bhi,
        const unsigned short* __restrict__ Blo,
        float* __restrict__ C) {
    __shared__ float red[3][64][66];   // +2 pad -> 2-way bank aliasing (free)
    const int lane = threadIdx.x & 63;
    const int wv = threadIdx.x >> 6;   // wave 0..3 = K-slice
    const int r0 = blockIdx.x * 64;
    const int h0 = blockIdx.y * 64;
    const int lr = lane & 15;          // fragment row/col
    const int lk = (lane >> 4) * 8;    // fragment k offset

    const f32x4 z4 = {0.f, 0.f, 0.f, 0.f};
    const bf16x8 zb = {0, 0, 0, 0, 0, 0, 0, 0};
    f32x4 acc[4][4];
#pragma unroll
    for (int i = 0; i < 4; ++i)
#pragma unroll
        for (int j = 0; j < 4; ++j) acc[i][j] = z4;

    const int k0 = wv * (KDIM / 4);    // 288 per wave
    for (int s = 0; s < 9; ++s) {
        const int kk = k0 + s * 32;
        const int tap = kk / F_;             // 0..2 (32 | 384, no straddle)
        const int fo = kk - tap * F_ + lk;   // f offset for this lane
        bf16x8 ah[4], al[4];
#pragma unroll
        for (int mi = 0; mi < 4; ++mi) {
            const int row = r0 + mi * 16 + lr;          // global row = b*512+l
            const int sl = (row & (L_ - 1)) + tap - 1;  // x row within batch
            if ((unsigned)sl < (unsigned)L_) {
                const int off = ((row & ~(L_ - 1)) + sl) * F_ + fo;
                ah[mi] = *(const bf16x8*)(Ahi + off);
                al[mi] = *(const bf16x8*)(Alo + off);
            } else {
                ah[mi] = zb;
                al[mi] = zb;
            }
        }
#pragma unroll
        for (int ni = 0; ni < 4; ++ni) {
            const int h = h0 + ni * 16 + lr;
            const int boff = h * KDIM + tap * F_ + fo;
            const bf16x8 bh = *(const bf16x8*)(Bhi + boff);
            const bf16x8 bl = *(const bf16x8*)(Blo + boff);
#pragma unroll
            for (int mi = 0; mi < 4; ++mi) {
                acc[mi][ni] = __builtin_amdgcn_mfma_f32_16x16x32_bf16(ah[mi], bh, acc[mi][ni], 0, 0, 0);
                acc[mi][ni] = __builtin_amdgcn_mfma_f32_16x16x32_bf16(ah[mi], bl, acc[mi][ni], 0, 0, 0);
                acc[mi][ni] = __builtin_amdgcn_mfma_f32_16x16x32_bf16(al[mi], bh, acc[mi][ni], 0, 0, 0);
            }
        }
    }

    // split-K reduction: waves 1-3 dump partials to LDS, wave 0 sums + stores.
    // C/D layout (verified): col = lane&15, row = (lane>>4)*4 + reg.
    const int rbase = (lane >> 4) * 4;
    if (wv > 0) {
#pragma unroll
        for (int mi = 0; mi < 4; ++mi)
#pragma unroll
            for (int ni = 0; ni < 4; ++ni)
#pragma unroll
                for (int r = 0; r < 4; ++r)
                    red[wv - 1][mi * 16 + rbase + r][ni * 16 + lr] = acc[mi][ni][r];
    }
    __syncthreads();
    if (wv == 0) {
#pragma unroll
        for (int mi = 0; mi < 4; ++mi)
#pragma unroll
            for (int ni = 0; ni < 4; ++ni)
#pragma unroll
                for (int r = 0; r < 4; ++r) {
                    const int rr = mi * 16 + rbase + r;
                    const int cc = ni * 16 + lr;
                    float v = acc[mi][ni][r]
                            + red[0][rr][cc] + red[1][rr][cc] + red[2][rr][cc];
                    C[(r0 + rr) * H_ + h0 + cc] = v;
                }
    }
}

// ---------------------------------------------------------------------------
// Kernel 4: bias + LayerNorm + ReLU over raw conv1 output, re-split to bf16
// hi/lo planes for conv2's A operand. One wave per row (384 channels).
// ---------------------------------------------------------------------------
__global__ __launch_bounds__(256) void k_lnrelu(
        const float* __restrict__ c, const float* __restrict__ cb,
        const float* __restrict__ g, const float* __restrict__ bt,
        unsigned short* __restrict__ oh, unsigned short* __restrict__ ol) {
    const int row = blockIdx.x * 4 + (threadIdx.x >> 6);
    const int lane = threadIdx.x & 63;
    const float* cr = c + (long)row * H_;
    float2 dv[3];
    dv[0] = ((const float2*)cr)[lane];
    dv[1] = ((const float2*)cr)[lane + 64];
    dv[2] = ((const float2*)cr)[lane + 128];
#pragma unroll
    for (int p = 0; p < 3; ++p) {
        const int ch = 2 * (lane + 64 * p);
        dv[p].x += cb[ch];
        dv[p].y += cb[ch + 1];
    }
    float s = dv[0].x + dv[0].y + dv[1].x + dv[1].y + dv[2].x + dv[2].y;
    float s2 = dv[0].x * dv[0].x + dv[0].y * dv[0].y + dv[1].x * dv[1].x
             + dv[1].y * dv[1].y + dv[2].x * dv[2].x + dv[2].y * dv[2].y;
    for (int off = 32; off >= 1; off >>= 1) {
        s += __shfl_xor(s, off);
        s2 += __shfl_xor(s2, off);
    }
    const float mu = s * (1.f / H_);
    const float var = s2 * (1.f / H_) - mu * mu;
    const float rs = rsqrtf(var + EPS_);
#pragma unroll
    for (int p = 0; p < 3; ++p) {
        const int ch = 2 * (lane + 64 * p);
        float r0 = fmaxf((dv[p].x - mu) * rs * g[ch] + bt[ch], 0.f);
        float r1 = fmaxf((dv[p].y - mu) * rs * g[ch + 1] + bt[ch + 1], 0.f);
        ushort2 hv, lv;
        bf16_split(r0, hv.x, lv.x);
        bf16_split(r1, hv.y, lv.y);
        *(ushort2*)(oh + (long)row * H_ + ch) = hv;
        *(ushort2*)(ol + (long)row * H_ + ch) = lv;
    }
}

// ---------------------------------------------------------------------------
// Kernel 5: bias + LayerNorm + ReLU + linear + ReLU + exp -> durations.
// ---------------------------------------------------------------------------
__global__ __launch_bounds__(256) void k_fin(
        const float* __restrict__ c, const float* __restrict__ cb,
        const float* __restrict__ g, const float* __restrict__ bt,
        const float* __restrict__ lw, const float* __restrict__ lb,
        float* __restrict__ dur) {
    const int row = blockIdx.x * 4 + (threadIdx.x >> 6);
    const int lane = threadIdx.x & 63;
    const float* cr = c + (long)row * F_;
    float2 dv[3];
    dv[0] = ((const float2*)cr)[lane];
    dv[1] = ((const float2*)cr)[lane + 64];
    dv[2] = ((const float2*)cr)[lane + 128];
#pragma unroll
    for (int p = 0; p < 3; ++p) {
        const int ch = 2 * (lane + 64 * p);
        dv[p].x += cb[ch];
        dv[p].y += cb[ch + 1];
    }
    float s = dv[0].x + dv[0].y + dv[1].x + dv[1].y + dv[2].x + dv[2].y;
    float s2 = dv[0].x * dv[0].x + dv[0].y * dv[0].y + dv[1].x * dv[1].x
             + dv[1].y * dv[1].y + dv[2].x * dv[2].x + dv[2].y * dv[2].y;
    for (int off = 32; off >= 1; off >>= 1) {
        s += __shfl_xor(s, off);
        s2 += __shfl_xor(s2, off);
    }
    const float mu = s * (1.f / F_);
    const float var = s2 * (1.f / F_) - mu * mu;
    const float rs = rsqrtf(var + EPS_);
    float dot = 0.f;
#pragma unroll
    for (int p = 0; p < 3; ++p) {
        const int ch = 2 * (lane + 64 * p);
        float r0 = fmaxf((dv[p].x - mu) * rs * g[ch] + bt[ch], 0.f);
        float r1 = fmaxf((dv[p].y - mu) * rs * g[ch + 1] + bt[ch + 1], 0.f);
        dot += r0 * lw[ch] + r1 * lw[ch + 1];
    }
    for (int off = 32; off >= 1; off >>= 1) dot += __shfl_xor(dot, off);
    if (lane == 0) dur[row] = expf(fmaxf(dot + lb[0], 0.f));
}

// ---------------------------------------------------------------------------
// Kernel 6: length-regulate gather (unchanged; memory bound).
// ---------------------------------------------------------------------------
__global__ void k_gather(const float4* __restrict__ x, const int* __restrict__ idx,
                         float4* __restrict__ out) {
    const int F4 = F_ / 4;                        // 96
    const int total = B_ * MAX_OUT_ * F4;
    for (int i = blockIdx.x * blockDim.x + threadIdx.x; i < total;
         i += gridDim.x * blockDim.x) {
        int row = i / F4;
        int f4 = i - row * F4;
        int t = row % MAX_OUT_;
        int b = row / MAX_OUT_;
        int id = idx[b * MAX_OUT_ + t];
        float4 v = make_float4(0.f, 0.f, 0.f, 0.f);
        if (id >= 0) v = x[((long)b * L_ + id) * F4 + f4];
        out[i] = v;
    }
}

// ---------------------------------------------------------------------------
extern "C" void kernel_launch(void* const* d_in, const int* in_sizes, int n_in,
                              void* d_out, int out_size, void* d_ws, size_t ws_size,
                              hipStream_t stream) {
    const float* input   = (const float*)d_in[0];
    const int*   target  = (const int*)d_in[1];
    const float* conv1_w = (const float*)d_in[2];
    const float* conv1_b = (const float*)d_in[3];
    const float* ln1_g   = (const float*)d_in[4];
    const float* ln1_b   = (const float*)d_in[5];
    const float* conv2_w = (const float*)d_in[6];
    const float* conv2_b = (const float*)d_in[7];
    const float* ln2_g   = (const float*)d_in[8];
    const float* ln2_b   = (const float*)d_in[9];
    const float* lin_w   = (const float*)d_in[10];
    const float* lin_b   = (const float*)d_in[11];

    float* out0 = (float*)d_out;                                  // [B, 4096, F]
    float* dur  = out0 + (size_t)B_ * MAX_OUT_ * F_;              // [B, L]
    // Raw conv outputs scratched inside out0 (fully overwritten by k_gather).
    float* c    = out0;                                           // [8192][384] f32

    // workspace: idx (256KB) + x/h1 hi+lo planes (12.58MB) + weight planes
    // (3.54MB) = 15.63MB total (previous kernel already assumed ~16.5MB).
    char* ws = (char*)d_ws;
    int* idx = (int*)ws;                                          // 262144 B
    unsigned short* xh  = (unsigned short*)(ws + 262144);
    unsigned short* xl  = xh + NXE;
    unsigned short* w1h = xl + NXE;
    unsigned short* w1l = w1h + NW;
    unsigned short* w2h = w1l + NW;
    unsigned short* w2l = w2h + NW;

    hipLaunchKernelGGL(k_scan_idx, dim3(B_), dim3(L_), 0, stream, target, idx);
    hipLaunchKernelGGL(k_prep, dim3(2048), dim3(256), 0, stream,
                       input, conv1_w, conv2_w, xh, xl, w1h, w1l, w2h, w2l);
    // conv1: raw output into out0 scratch
    hipLaunchKernelGGL(k_gemm, dim3(M_TOTAL / 64, H_ / 64), dim3(256), 0, stream,
                       xh, xl, w1h, w1l, c);
    // bias+LN+ReLU, re-split into the (now dead) x planes as conv2's input
    hipLaunchKernelGGL(k_lnrelu, dim3(M_TOTAL / 4), dim3(256), 0, stream,
                       c, conv1_b, ln1_g, ln1_b, xh, xl);
    // conv2: raw output into out0 scratch
    hipLaunchKernelGGL(k_gemm, dim3(M_TOTAL / 64, H_ / 64), dim3(256), 0, stream,
                       xh, xl, w2h, w2l, c);
    // bias+LN+ReLU+linear+ReLU+exp -> durations
    hipLaunchKernelGGL(k_fin, dim3(M_TOTAL / 4), dim3(256), 0, stream,
                       c, conv2_b, ln2_g, ln2_b, lin_w, lin_b, dur);
    // finally overwrite out0 with the gather
    hipLaunchKernelGGL(k_gather, dim3(4096), dim3(256), 0, stream,
                       (const float4*)input, idx, (float4*)out0);
}

// Round 2
// 158.407 us; speedup vs baseline: 6.7440x; 1.0029x over previous
//
#include <hip/hip_runtime.h>
#include <math.h>

// Problem constants
#define B_ 16
#define L_ 512
#define F_ 384
#define H_ 384
#define K_ 3
#define MAX_OUT_ 4096
#define EPS_ 1e-5f

#define APAD (L_ + 2)                 // padded rows per batch (zero guards at 0 and 513)
#define M_TOTAL (B_ * L_)             // 8192 gemm rows
#define KDIM (K_ * F_)                // 1152 gemm K
#define NW (H_ * F_ * K_)             // 442368 weight elems per conv
#define NXE (B_ * L_ * F_)            // 3145728 activation elems
#define NXP (B_ * APAD * F_)          // 3158016 padded activation elems

typedef __attribute__((ext_vector_type(8))) short bf16x8;   // 8 bf16 = 4 VGPR
typedef __attribute__((ext_vector_type(4))) float f32x4;

// ---------------------------------------------------------------------------
// bf16 split helpers: v = hi + lo with RNE rounding (3-term product error ~2^-17)
// ---------------------------------------------------------------------------
__device__ inline unsigned short bf16_rne(float v) {
    unsigned int u = __float_as_uint(v);
    unsigned int r = (u + 0x7fffu + ((u >> 16) & 1u)) >> 16;
    return (unsigned short)r;
}
__device__ inline void bf16_split(float v, unsigned short& hi, unsigned short& lo) {
    hi = bf16_rne(v);
    float hf = __uint_as_float(((unsigned int)hi) << 16);
    lo = bf16_rne(v - hf);
}

// ---------------------------------------------------------------------------
// Kernel 1: per-batch cumsum of target + searchsorted index table (unchanged).
// ---------------------------------------------------------------------------
__global__ void k_scan_idx(const int* __restrict__ target, int* __restrict__ idx) {
    __shared__ int e[L_];
    const int b = blockIdx.x;
    const int tid = threadIdx.x;   // blockDim = 512 = L_
    e[tid] = target[b * L_ + tid];
    __syncthreads();
    for (int off = 1; off < L_; off <<= 1) {
        int add = (tid >= off) ? e[tid - off] : 0;
        __syncthreads();
        e[tid] += add;
        __syncthreads();
    }
    const int total = e[L_ - 1];
    for (int t = tid; t < MAX_OUT_; t += L_) {
        int lo = 0, hi = L_;
        while (lo < hi) {
            int m = (lo + hi) >> 1;
            if (e[m] <= t) lo = m + 1; else hi = m;
        }
        int v = (t < total) ? min(lo, L_ - 1) : -1;
        idx[b * MAX_OUT_ + t] = v;
    }
}

// ---------------------------------------------------------------------------
// Kernel 2: prep — split input x into PADDED bf16 hi/lo planes [B][514][F]
// (guard rows zeroed so the conv becomes a pure linear GEMM on the padded
// layout); transpose+split both conv weights to [h][tap*384+f] hi/lo planes.
// ---------------------------------------------------------------------------
__global__ void k_prep(const float* __restrict__ x,
                       const float* __restrict__ w1, const float* __restrict__ w2,
                       unsigned short* __restrict__ xh, unsigned short* __restrict__ xl,
                       unsigned short* __restrict__ w1h, unsigned short* __restrict__ w1l,
                       unsigned short* __restrict__ w2h, unsigned short* __restrict__ w2l) {
    const int NX4 = NXE / 4;               // 786432 float4s of x
    const int G4 = B_ * 2 * (F_ / 4);      // 3072 guard ushort4s per plane
    const int total = NX4 + G4 + 2 * NW;
    for (int i = blockIdx.x * blockDim.x + threadIdx.x; i < total;
         i += gridDim.x * blockDim.x) {
        if (i < NX4) {
            const int fi = i % (F_ / 4);
            const int row = i / (F_ / 4);          // global row 0..8191
            const int b = row >> 9;
            const int l = row & (L_ - 1);
            const int po = (b * APAD + l + 1) * (F_ / 4) + fi;
            float4 v = ((const float4*)x)[i];
            ushort4 hv, lv;
            bf16_split(v.x, hv.x, lv.x);
            bf16_split(v.y, hv.y, lv.y);
            bf16_split(v.z, hv.z, lv.z);
            bf16_split(v.w, hv.w, lv.w);
            ((ushort4*)xh)[po] = hv;
            ((ushort4*)xl)[po] = lv;
        } else if (i < NX4 + G4) {
            const int j = i - NX4;
            const int b = j / (2 * (F_ / 4));
            const int r = j % (2 * (F_ / 4));
            const int grow = (r < (F_ / 4)) ? 0 : (APAD - 1);
            const int fi = r % (F_ / 4);
            const int po = (b * APAD + grow) * (F_ / 4) + fi;
            const ushort4 z = {0, 0, 0, 0};
            ((ushort4*)xh)[po] = z;
            ((ushort4*)xl)[po] = z;
        } else {
            int j = i - NX4 - G4;
            const float* w = (j < NW) ? w1 : w2;
            unsigned short* ohp = (j < NW) ? w1h : w2h;
            unsigned short* olp = (j < NW) ? w1l : w2l;
            int o = (j < NW) ? j : j - NW;
            int h = o / KDIM;
            int rem = o - h * KDIM;
            int k = rem / F_;                      // tap
            int f = rem - k * F_;
            unsigned short hi, lo;
            bf16_split(w[(h * F_ + f) * K_ + k], hi, lo);
            ohp[o] = hi;
            olp[o] = lo;
        }
    }
}

// ---------------------------------------------------------------------------
// Kernel 3: conv-as-GEMM via split-bf16 MFMA (3 terms: hh + hl + lh).
// Padded A layout makes addressing purely linear: A[r][k] = xpad[rowpad(r)*384+k].
// Block = 256 thr (4 waves), tile 64 rows x 64 channels, split-K 288/wave.
// Software-pipelined: double-buffered fragment registers, loads for step s+1
// issued before MFMAs of step s (immediate-offset loads, no per-step VALU).
// Epilogue: 2-round pairwise split-K reduction, all waves active.
// ---------------------------------------------------------------------------
#define LOADS(S, AH, AL, BH, BL)                                           \
    _Pragma("unroll")                                                      \
    for (int q = 0; q < 4; ++q) {                                          \
        AH[q] = *(const bf16x8*)(Ahi + aoff[q] + (S) * 32);                \
        AL[q] = *(const bf16x8*)(Alo + aoff[q] + (S) * 32);                \
        BH[q] = *(const bf16x8*)(Bhi + boff[q] + (S) * 32);                \
        BL[q] = *(const bf16x8*)(Blo + boff[q] + (S) * 32);                \
    }

#define MFMAS(AH, AL, BH, BL)                                              \
    _Pragma("unroll")                                                      \
    for (int ni = 0; ni < 4; ++ni) {                                       \
        _Pragma("unroll")                                                  \
        for (int mi = 0; mi < 4; ++mi) {                                   \
            acc[mi][ni] = __builtin_amdgcn_mfma_f32_16x16x32_bf16(         \
                AH[mi], BH[ni], acc[mi][ni], 0, 0, 0);                     \
            acc[mi][ni] = __builtin_amdgcn_mfma_f32_16x16x32_bf16(         \
                AH[mi], BL[ni], acc[mi][ni], 0, 0, 0);                     \
            acc[mi][ni] = __builtin_amdgcn_mfma_f32_16x16x32_bf16(         \
                AL[mi], BH[ni], acc[mi][ni], 0, 0, 0);                     \
        }                                                                  \
    }

__global__ __launch_bounds__(256, 2) void k_gemm(
        const unsigned short* __restrict__ Ahi,
        const unsigned short* __restrict__ Alo,
        const unsigned short* __restrict__ Bhi,
        const unsigned short* __restrict__ Blo,
        float* __restrict__ C) {
    __shared__ float red[2][64][66];       // 33.8 KB; 66-pad -> 2-way (free)
    const int lane = threadIdx.x & 63;
    const int wv = threadIdx.x >> 6;       // wave 0..3 = K-slice
    const int r0 = blockIdx.x * 64;
    const int h0 = blockIdx.y * 64;
    const int lr = lane & 15;              // fragment row/col
    const int lk = (lane >> 4) * 8;        // fragment k offset
    const int k0 = wv * (KDIM / 4);        // 288 per wave

    const int b = r0 >> 9;                 // 64-row tiles never straddle batches
    const int l = r0 & (L_ - 1);

    int aoff[4], boff[4];
#pragma unroll
    for (int q = 0; q < 4; ++q) {
        aoff[q] = (b * APAD + l + q * 16 + lr) * F_ + k0 + lk;
        boff[q] = (h0 + q * 16 + lr) * KDIM + k0 + lk;
    }

    const f32x4 z4 = {0.f, 0.f, 0.f, 0.f};
    f32x4 acc[4][4];
#pragma unroll
    for (int i = 0; i < 4; ++i)
#pragma unroll
        for (int j = 0; j < 4; ++j) acc[i][j] = z4;

    bf16x8 Ah0[4], Al0[4], Bh0[4], Bl0[4];
    bf16x8 Ah1[4], Al1[4], Bh1[4], Bl1[4];

    // pipelined K-loop: 9 steps of K=32, depth-1 register double buffer
    LOADS(0, Ah0, Al0, Bh0, Bl0);
#pragma unroll
    for (int s = 0; s < 8; s += 2) {
        LOADS(s + 1, Ah1, Al1, Bh1, Bl1);
        MFMAS(Ah0, Al0, Bh0, Bl0);
        LOADS(s + 2, Ah0, Al0, Bh0, Bl0);
        MFMAS(Ah1, Al1, Bh1, Bl1);
    }
    MFMAS(Ah0, Al0, Bh0, Bl0);

    // ---- split-K reduction, 2 pairwise rounds, all waves active ----
    // C/D layout: col = lane&15, row = (lane>>4)*4 + reg.
    const int rb = (lane >> 4) * 4;
    if (wv >= 2) {
#pragma unroll
        for (int mi = 0; mi < 4; ++mi)
#pragma unroll
            for (int ni = 0; ni < 4; ++ni)
#pragma unroll
                for (int r = 0; r < 4; ++r)
                    red[wv - 2][mi * 16 + rb + r][ni * 16 + lr] = acc[mi][ni][r];
    }
    __syncthreads();
    if (wv < 2) {
#pragma unroll
        for (int mi = 0; mi < 4; ++mi)
#pragma unroll
            for (int ni = 0; ni < 4; ++ni)
#pragma unroll
                for (int r = 0; r < 4; ++r)
                    acc[mi][ni][r] += red[wv][mi * 16 + rb + r][ni * 16 + lr];
    }
    __syncthreads();
    // round 2: wave1 publishes rows 0..31, wave0 publishes rows 32..63
    if (wv == 1) {
#pragma unroll
        for (int mi = 0; mi < 2; ++mi)
#pragma unroll
            for (int ni = 0; ni < 4; ++ni)
#pragma unroll
                for (int r = 0; r < 4; ++r)
                    red[0][mi * 16 + rb + r][ni * 16 + lr] = acc[mi][ni][r];
    }
    if (wv == 0) {
#pragma unroll
        for (int mi = 2; mi < 4; ++mi)
#pragma unroll
            for (int ni = 0; ni < 4; ++ni)
#pragma unroll
                for (int r = 0; r < 4; ++r)
                    red[0][mi * 16 + rb + r][ni * 16 + lr] = acc[mi][ni][r];
    }
    __syncthreads();
    if (wv == 0) {     // stores rows 0..31
#pragma unroll
        for (int mi = 0; mi < 2; ++mi)
#pragma unroll
            for (int ni = 0; ni < 4; ++ni)
#pragma unroll
                for (int r = 0; r < 4; ++r) {
                    const int rr = mi * 16 + rb + r;
                    const int cc = ni * 16 + lr;
                    C[(r0 + rr) * H_ + h0 + cc] = acc[mi][ni][r] + red[0][rr][cc];
                }
    }
    if (wv == 1) {     // stores rows 32..63
#pragma unroll
        for (int mi = 2; mi < 4; ++mi)
#pragma unroll
            for (int ni = 0; ni < 4; ++ni)
#pragma unroll
                for (int r = 0; r < 4; ++r) {
                    const int rr = mi * 16 + rb + r;
                    const int cc = ni * 16 + lr;
                    C[(r0 + rr) * H_ + h0 + cc] = acc[mi][ni][r] + red[0][rr][cc];
                }
    }
}

// ---------------------------------------------------------------------------
// Kernel 4: bias + LayerNorm + ReLU over raw conv1 output, re-split to PADDED
// bf16 hi/lo planes for conv2's A operand. One wave per row (384 channels).
// ---------------------------------------------------------------------------
__global__ __launch_bounds__(256) void k_lnrelu(
        const float* __restrict__ c, const float* __restrict__ cb,
        const float* __restrict__ g, const float* __restrict__ bt,
        unsigned short* __restrict__ oh, unsigned short* __restrict__ ol) {
    const int row = blockIdx.x * 4 + (threadIdx.x >> 6);
    const int lane = threadIdx.x & 63;
    const float* cr = c + (long)row * H_;
    float2 dv[3];
    dv[0] = ((const float2*)cr)[lane];
    dv[1] = ((const float2*)cr)[lane + 64];
    dv[2] = ((const float2*)cr)[lane + 128];
#pragma unroll
    for (int p = 0; p < 3; ++p) {
        const int ch = 2 * (lane + 64 * p);
        dv[p].x += cb[ch];
        dv[p].y += cb[ch + 1];
    }
    float s = dv[0].x + dv[0].y + dv[1].x + dv[1].y + dv[2].x + dv[2].y;
    float s2 = dv[0].x * dv[0].x + dv[0].y * dv[0].y + dv[1].x * dv[1].x
             + dv[1].y * dv[1].y + dv[2].x * dv[2].x + dv[2].y * dv[2].y;
    for (int off = 32; off >= 1; off >>= 1) {
        s += __shfl_xor(s, off);
        s2 += __shfl_xor(s2, off);
    }
    const float mu = s * (1.f / H_);
    const float var = s2 * (1.f / H_) - mu * mu;
    const float rs = rsqrtf(var + EPS_);
    const int bpo = (row >> 9) * APAD + (row & (L_ - 1)) + 1;   // padded row
    const long po = (long)bpo * H_;
#pragma unroll
    for (int p = 0; p < 3; ++p) {
        const int ch = 2 * (lane + 64 * p);
        float r0 = fmaxf((dv[p].x - mu) * rs * g[ch] + bt[ch], 0.f);
        float r1 = fmaxf((dv[p].y - mu) * rs * g[ch + 1] + bt[ch + 1], 0.f);
        ushort2 hv, lv;
        bf16_split(r0, hv.x, lv.x);
        bf16_split(r1, hv.y, lv.y);
        *(ushort2*)(oh + po + ch) = hv;
        *(ushort2*)(ol + po + ch) = lv;
    }
}

// ---------------------------------------------------------------------------
// Kernel 5: bias + LayerNorm + ReLU + linear + ReLU + exp -> durations.
// ---------------------------------------------------------------------------
__global__ __launch_bounds__(256) void k_fin(
        const float* __restrict__ c, const float* __restrict__ cb,
        const float* __restrict__ g, const float* __restrict__ bt,
        const float* __restrict__ lw, const float* __restrict__ lb,
        float* __restrict__ dur) {
    const int row = blockIdx.x * 4 + (threadIdx.x >> 6);
    const int lane = threadIdx.x & 63;
    const float* cr = c + (long)row * F_;
    float2 dv[3];
    dv[0] = ((const float2*)cr)[lane];
    dv[1] = ((const float2*)cr)[lane + 64];
    dv[2] = ((const float2*)cr)[lane + 128];
#pragma unroll
    for (int p = 0; p < 3; ++p) {
        const int ch = 2 * (lane + 64 * p);
        dv[p].x += cb[ch];
        dv[p].y += cb[ch + 1];
    }
    float s = dv[0].x + dv[0].y + dv[1].x + dv[1].y + dv[2].x + dv[2].y;
    float s2 = dv[0].x * dv[0].x + dv[0].y * dv[0].y + dv[1].x * dv[1].x
             + dv[1].y * dv[1].y + dv[2].x * dv[2].x + dv[2].y * dv[2].y;
    for (int off = 32; off >= 1; off >>= 1) {
        s += __shfl_xor(s, off);
        s2 += __shfl_xor(s2, off);
    }
    const float mu = s * (1.f / F_);
    const float var = s2 * (1.f / F_) - mu * mu;
    const float rs = rsqrtf(var + EPS_);
    float dot = 0.f;
#pragma unroll
    for (int p = 0; p < 3; ++p) {
        const int ch = 2 * (lane + 64 * p);
        float r0 = fmaxf((dv[p].x - mu) * rs * g[ch] + bt[ch], 0.f);
        float r1 = fmaxf((dv[p].y - mu) * rs * g[ch + 1] + bt[ch + 1], 0.f);
        dot += r0 * lw[ch] + r1 * lw[ch + 1];
    }
    for (int off = 32; off >= 1; off >>= 1) dot += __shfl_xor(dot, off);
    if (lane == 0) dur[row] = expf(fmaxf(dot + lb[0], 0.f));
}

// ---------------------------------------------------------------------------
// Kernel 6: length-regulate gather (memory bound, unchanged).
// ---------------------------------------------------------------------------
__global__ void k_gather(const float4* __restrict__ x, const int* __restrict__ idx,
                         float4* __restrict__ out) {
    const int F4 = F_ / 4;                        // 96
    const int total = B_ * MAX_OUT_ * F4;
    for (int i = blockIdx.x * blockDim.x + threadIdx.x; i < total;
         i += gridDim.x * blockDim.x) {
        int row = i / F4;
        int f4 = i - row * F4;
        int t = row % MAX_OUT_;
        int b = row / MAX_OUT_;
        int id = idx[b * MAX_OUT_ + t];
        float4 v = make_float4(0.f, 0.f, 0.f, 0.f);
        if (id >= 0) v = x[((long)b * L_ + id) * F4 + f4];
        out[i] = v;
    }
}

// ---------------------------------------------------------------------------
extern "C" void kernel_launch(void* const* d_in, const int* in_sizes, int n_in,
                              void* d_out, int out_size, void* d_ws, size_t ws_size,
                              hipStream_t stream) {
    const float* input   = (const float*)d_in[0];
    const int*   target  = (const int*)d_in[1];
    const float* conv1_w = (const float*)d_in[2];
    const float* conv1_b = (const float*)d_in[3];
    const float* ln1_g   = (const float*)d_in[4];
    const float* ln1_b   = (const float*)d_in[5];
    const float* conv2_w = (const float*)d_in[6];
    const float* conv2_b = (const float*)d_in[7];
    const float* ln2_g   = (const float*)d_in[8];
    const float* ln2_b   = (const float*)d_in[9];
    const float* lin_w   = (const float*)d_in[10];
    const float* lin_b   = (const float*)d_in[11];

    float* out0 = (float*)d_out;                                  // [B, 4096, F]
    float* dur  = out0 + (size_t)B_ * MAX_OUT_ * F_;              // [B, L]
    float* c    = out0;   // raw conv outputs scratched in out0 (overwritten by gather)

    // workspace: idx 256KB + padded x/h1 planes 12.63MB + weight planes 3.54MB
    char* ws = (char*)d_ws;
    int* idx = (int*)ws;                                          // 262144 B
    unsigned short* xh  = (unsigned short*)(ws + 262144);
    unsigned short* xl  = xh + NXP;
    unsigned short* w1h = xl + NXP;
    unsigned short* w1l = w1h + NW;
    unsigned short* w2h = w1l + NW;
    unsigned short* w2l = w2h + NW;

    hipLaunchKernelGGL(k_scan_idx, dim3(B_), dim3(L_), 0, stream, target, idx);
    hipLaunchKernelGGL(k_prep, dim3(2048), dim3(256), 0, stream,
                       input, conv1_w, conv2_w, xh, xl, w1h, w1l, w2h, w2l);
    // conv1: raw output into out0 scratch
    hipLaunchKernelGGL(k_gemm, dim3(M_TOTAL / 64, H_ / 64), dim3(256), 0, stream,
                       xh, xl, w1h, w1l, c);
    // bias+LN+ReLU, re-split into the (now dead) padded x planes
    hipLaunchKernelGGL(k_lnrelu, dim3(M_TOTAL / 4), dim3(256), 0, stream,
                       c, conv1_b, ln1_g, ln1_b, xh, xl);
    // conv2: raw output into out0 scratch
    hipLaunchKernelGGL(k_gemm, dim3(M_TOTAL / 64, H_ / 64), dim3(256), 0, stream,
                       xh, xl, w2h, w2l, c);
    // bias+LN+ReLU+linear+ReLU+exp -> durations
    hipLaunchKernelGGL(k_fin, dim3(M_TOTAL / 4), dim3(256), 0, stream,
                       c, conv2_b, ln2_g, ln2_b, lin_w, lin_b, dur);
    // finally overwrite out0 with the gather
    hipLaunchKernelGGL(k_gather, dim3(4096), dim3(256), 0, stream,
                       (const float4*)input, idx, (float4*)out0);
}

// Round 3
// 156.601 us; speedup vs baseline: 6.8218x; 1.0115x over previous
//
#include <hip/hip_runtime.h>
#include <math.h>

// Problem constants
#define B_ 16
#define L_ 512
#define F_ 384
#define H_ 384
#define K_ 3
#define MAX_OUT_ 4096
#define EPS_ 1e-5f

#define APAD (L_ + 2)                 // padded rows per batch (zero guards at 0 and 513)
#define M_TOTAL (B_ * L_)             // 8192 gemm rows
#define KDIM (K_ * F_)                // 1152 gemm K
#define NW (H_ * F_ * K_)             // 442368 weight elems per conv
#define NXE (B_ * L_ * F_)            // 3145728 activation elems
#define NXP (B_ * APAD * F_)          // 3158016 padded activation elems

typedef __attribute__((ext_vector_type(8))) short bf16x8;   // 8 bf16 = 4 VGPR
typedef __attribute__((ext_vector_type(4))) float f32x4;

// ---------------------------------------------------------------------------
// bf16 split helpers: v = hi + lo with RNE rounding (3-term product error ~2^-17)
// ---------------------------------------------------------------------------
__device__ inline unsigned short bf16_rne(float v) {
    unsigned int u = __float_as_uint(v);
    unsigned int r = (u + 0x7fffu + ((u >> 16) & 1u)) >> 16;
    return (unsigned short)r;
}
__device__ inline void bf16_split(float v, unsigned short& hi, unsigned short& lo) {
    hi = bf16_rne(v);
    float hf = __uint_as_float(((unsigned int)hi) << 16);
    lo = bf16_rne(v - hf);
}

// ---------------------------------------------------------------------------
// Kernel 1: per-batch cumsum of target + searchsorted index table (unchanged).
// ---------------------------------------------------------------------------
__global__ void k_scan_idx(const int* __restrict__ target, int* __restrict__ idx) {
    __shared__ int e[L_];
    const int b = blockIdx.x;
    const int tid = threadIdx.x;   // blockDim = 512 = L_
    e[tid] = target[b * L_ + tid];
    __syncthreads();
    for (int off = 1; off < L_; off <<= 1) {
        int add = (tid >= off) ? e[tid - off] : 0;
        __syncthreads();
        e[tid] += add;
        __syncthreads();
    }
    const int total = e[L_ - 1];
    for (int t = tid; t < MAX_OUT_; t += L_) {
        int lo = 0, hi = L_;
        while (lo < hi) {
            int m = (lo + hi) >> 1;
            if (e[m] <= t) lo = m + 1; else hi = m;
        }
        int v = (t < total) ? min(lo, L_ - 1) : -1;
        idx[b * MAX_OUT_ + t] = v;
    }
}

// ---------------------------------------------------------------------------
// Kernel 2: prep — split input x into PADDED bf16 hi/lo planes [B][514][F];
// transpose+split both conv weights to [h][tap*384+f] hi/lo planes.
// ---------------------------------------------------------------------------
__global__ void k_prep(const float* __restrict__ x,
                       const float* __restrict__ w1, const float* __restrict__ w2,
                       unsigned short* __restrict__ xh, unsigned short* __restrict__ xl,
                       unsigned short* __restrict__ w1h, unsigned short* __restrict__ w1l,
                       unsigned short* __restrict__ w2h, unsigned short* __restrict__ w2l) {
    const int NX4 = NXE / 4;               // 786432 float4s of x
    const int G4 = B_ * 2 * (F_ / 4);      // 3072 guard ushort4s per plane
    const int total = NX4 + G4 + 2 * NW;
    for (int i = blockIdx.x * blockDim.x + threadIdx.x; i < total;
         i += gridDim.x * blockDim.x) {
        if (i < NX4) {
            const int fi = i % (F_ / 4);
            const int row = i / (F_ / 4);          // global row 0..8191
            const int b = row >> 9;
            const int l = row & (L_ - 1);
            const int po = (b * APAD + l + 1) * (F_ / 4) + fi;
            float4 v = ((const float4*)x)[i];
            ushort4 hv, lv;
            bf16_split(v.x, hv.x, lv.x);
            bf16_split(v.y, hv.y, lv.y);
            bf16_split(v.z, hv.z, lv.z);
            bf16_split(v.w, hv.w, lv.w);
            ((ushort4*)xh)[po] = hv;
            ((ushort4*)xl)[po] = lv;
        } else if (i < NX4 + G4) {
            const int j = i - NX4;
            const int b = j / (2 * (F_ / 4));
            const int r = j % (2 * (F_ / 4));
            const int grow = (r < (F_ / 4)) ? 0 : (APAD - 1);
            const int fi = r % (F_ / 4);
            const int po = (b * APAD + grow) * (F_ / 4) + fi;
            const ushort4 z = {0, 0, 0, 0};
            ((ushort4*)xh)[po] = z;
            ((ushort4*)xl)[po] = z;
        } else {
            int j = i - NX4 - G4;
            const float* w = (j < NW) ? w1 : w2;
            unsigned short* ohp = (j < NW) ? w1h : w2h;
            unsigned short* olp = (j < NW) ? w1l : w2l;
            int o = (j < NW) ? j : j - NW;
            int h = o / KDIM;
            int rem = o - h * KDIM;
            int k = rem / F_;                      // tap
            int f = rem - k * F_;
            unsigned short hi, lo;
            bf16_split(w[(h * F_ + f) * K_ + k], hi, lo);
            ohp[o] = hi;
            olp[o] = lo;
        }
    }
}

// ---------------------------------------------------------------------------
// Kernel 3: conv-as-GEMM via split-bf16 MFMA (3 terms: hh + hl + lh).
// Block = 256 thr (4 waves), tile 64 rows x 64 channels, split-K 288/wave.
// K-loop: depth-1 register double buffer, PINNED with sched_barrier(0) after
// each load group so the compiler cannot sink loads into the MFMA clusters
// (round-2 evidence: VGPR_Count=72 -> buffers were not kept live). MFMAs are
// term-major so dependent MFMAs on one accumulator are 16 issues apart.
// ---------------------------------------------------------------------------
#define LOADS(S, AH, AL, BH, BL)                                           \
    _Pragma("unroll")                                                      \
    for (int q = 0; q < 4; ++q) {                                          \
        AH[q] = *(const bf16x8*)(Ahi + aoff[q] + (S) * 32);                \
        AL[q] = *(const bf16x8*)(Alo + aoff[q] + (S) * 32);                \
        BH[q] = *(const bf16x8*)(Bhi + boff[q] + (S) * 32);                \
        BL[q] = *(const bf16x8*)(Blo + boff[q] + (S) * 32);                \
    }

// term-major: 16 independent MFMAs between dependent writes to the same acc
#define MFMAS(AH, AL, BH, BL)                                              \
    _Pragma("unroll")                                                      \
    for (int ni = 0; ni < 4; ++ni)                                         \
        _Pragma("unroll")                                                  \
        for (int mi = 0; mi < 4; ++mi)                                     \
            acc[mi][ni] = __builtin_amdgcn_mfma_f32_16x16x32_bf16(         \
                AH[mi], BH[ni], acc[mi][ni], 0, 0, 0);                     \
    _Pragma("unroll")                                                      \
    for (int ni = 0; ni < 4; ++ni)                                         \
        _Pragma("unroll")                                                  \
        for (int mi = 0; mi < 4; ++mi)                                     \
            acc[mi][ni] = __builtin_amdgcn_mfma_f32_16x16x32_bf16(         \
                AH[mi], BL[ni], acc[mi][ni], 0, 0, 0);                     \
    _Pragma("unroll")                                                      \
    for (int ni = 0; ni < 4; ++ni)                                         \
        _Pragma("unroll")                                                  \
        for (int mi = 0; mi < 4; ++mi)                                     \
            acc[mi][ni] = __builtin_amdgcn_mfma_f32_16x16x32_bf16(         \
                AL[mi], BH[ni], acc[mi][ni], 0, 0, 0);

#define SB __builtin_amdgcn_sched_barrier(0)

__global__ __launch_bounds__(256, 2) void k_gemm(
        const unsigned short* __restrict__ Ahi,
        const unsigned short* __restrict__ Alo,
        const unsigned short* __restrict__ Bhi,
        const unsigned short* __restrict__ Blo,
        float* __restrict__ C) {
    __shared__ float red[2][64][66];       // 33.8 KB; 66-pad -> 2-way (free)
    const int lane = threadIdx.x & 63;
    const int wv = threadIdx.x >> 6;       // wave 0..3 = K-slice
    const int r0 = blockIdx.x * 64;
    const int h0 = blockIdx.y * 64;
    const int lr = lane & 15;              // fragment row/col
    const int lk = (lane >> 4) * 8;        // fragment k offset
    const int k0 = wv * (KDIM / 4);        // 288 per wave

    const int b = r0 >> 9;                 // 64-row tiles never straddle batches
    const int l = r0 & (L_ - 1);

    int aoff[4], boff[4];
#pragma unroll
    for (int q = 0; q < 4; ++q) {
        aoff[q] = (b * APAD + l + q * 16 + lr) * F_ + k0 + lk;
        boff[q] = (h0 + q * 16 + lr) * KDIM + k0 + lk;
    }

    const f32x4 z4 = {0.f, 0.f, 0.f, 0.f};
    f32x4 acc[4][4];
#pragma unroll
    for (int i = 0; i < 4; ++i)
#pragma unroll
        for (int j = 0; j < 4; ++j) acc[i][j] = z4;

    bf16x8 Ah0[4], Al0[4], Bh0[4], Bl0[4];
    bf16x8 Ah1[4], Al1[4], Bh1[4], Bl1[4];

    // 9 K-steps of 32, hand-unrolled depth-1 pipeline, sched_barrier-pinned.
    LOADS(0, Ah0, Al0, Bh0, Bl0); SB;
    LOADS(1, Ah1, Al1, Bh1, Bl1); SB;
    MFMAS(Ah0, Al0, Bh0, Bl0);
    LOADS(2, Ah0, Al0, Bh0, Bl0); SB;
    MFMAS(Ah1, Al1, Bh1, Bl1);
    LOADS(3, Ah1, Al1, Bh1, Bl1); SB;
    MFMAS(Ah0, Al0, Bh0, Bl0);
    LOADS(4, Ah0, Al0, Bh0, Bl0); SB;
    MFMAS(Ah1, Al1, Bh1, Bl1);
    LOADS(5, Ah1, Al1, Bh1, Bl1); SB;
    MFMAS(Ah0, Al0, Bh0, Bl0);
    LOADS(6, Ah0, Al0, Bh0, Bl0); SB;
    MFMAS(Ah1, Al1, Bh1, Bl1);
    LOADS(7, Ah1, Al1, Bh1, Bl1); SB;
    MFMAS(Ah0, Al0, Bh0, Bl0);
    LOADS(8, Ah0, Al0, Bh0, Bl0); SB;
    MFMAS(Ah1, Al1, Bh1, Bl1);
    SB;
    MFMAS(Ah0, Al0, Bh0, Bl0);

    // ---- split-K reduction, 2 pairwise rounds, all waves active ----
    // C/D layout: col = lane&15, row = (lane>>4)*4 + reg.
    const int rb = (lane >> 4) * 4;
    if (wv >= 2) {
#pragma unroll
        for (int mi = 0; mi < 4; ++mi)
#pragma unroll
            for (int ni = 0; ni < 4; ++ni)
#pragma unroll
                for (int r = 0; r < 4; ++r)
                    red[wv - 2][mi * 16 + rb + r][ni * 16 + lr] = acc[mi][ni][r];
    }
    __syncthreads();
    if (wv < 2) {
#pragma unroll
        for (int mi = 0; mi < 4; ++mi)
#pragma unroll
            for (int ni = 0; ni < 4; ++ni)
#pragma unroll
                for (int r = 0; r < 4; ++r)
                    acc[mi][ni][r] += red[wv][mi * 16 + rb + r][ni * 16 + lr];
    }
    __syncthreads();
    // round 2: wave1 publishes rows 0..31, wave0 publishes rows 32..63
    if (wv == 1) {
#pragma unroll
        for (int mi = 0; mi < 2; ++mi)
#pragma unroll
            for (int ni = 0; ni < 4; ++ni)
#pragma unroll
                for (int r = 0; r < 4; ++r)
                    red[0][mi * 16 + rb + r][ni * 16 + lr] = acc[mi][ni][r];
    }
    if (wv == 0) {
#pragma unroll
        for (int mi = 2; mi < 4; ++mi)
#pragma unroll
            for (int ni = 0; ni < 4; ++ni)
#pragma unroll
                for (int r = 0; r < 4; ++r)
                    red[0][mi * 16 + rb + r][ni * 16 + lr] = acc[mi][ni][r];
    }
    __syncthreads();
    if (wv == 0) {     // stores rows 0..31
#pragma unroll
        for (int mi = 0; mi < 2; ++mi)
#pragma unroll
            for (int ni = 0; ni < 4; ++ni)
#pragma unroll
                for (int r = 0; r < 4; ++r) {
                    const int rr = mi * 16 + rb + r;
                    const int cc = ni * 16 + lr;
                    C[(r0 + rr) * H_ + h0 + cc] = acc[mi][ni][r] + red[0][rr][cc];
                }
    }
    if (wv == 1) {     // stores rows 32..63
#pragma unroll
        for (int mi = 2; mi < 4; ++mi)
#pragma unroll
            for (int ni = 0; ni < 4; ++ni)
#pragma unroll
                for (int r = 0; r < 4; ++r) {
                    const int rr = mi * 16 + rb + r;
                    const int cc = ni * 16 + lr;
                    C[(r0 + rr) * H_ + h0 + cc] = acc[mi][ni][r] + red[0][rr][cc];
                }
    }
}

// ---------------------------------------------------------------------------
// Kernel 4: bias + LayerNorm + ReLU over raw conv1 output, re-split to PADDED
// bf16 hi/lo planes for conv2's A operand. One wave per row (384 channels).
// ---------------------------------------------------------------------------
__global__ __launch_bounds__(256) void k_lnrelu(
        const float* __restrict__ c, const float* __restrict__ cb,
        const float* __restrict__ g, const float* __restrict__ bt,
        unsigned short* __restrict__ oh, unsigned short* __restrict__ ol) {
    const int row = blockIdx.x * 4 + (threadIdx.x >> 6);
    const int lane = threadIdx.x & 63;
    const float* cr = c + (long)row * H_;
    float2 dv[3];
    dv[0] = ((const float2*)cr)[lane];
    dv[1] = ((const float2*)cr)[lane + 64];
    dv[2] = ((const float2*)cr)[lane + 128];
#pragma unroll
    for (int p = 0; p < 3; ++p) {
        const int ch = 2 * (lane + 64 * p);
        dv[p].x += cb[ch];
        dv[p].y += cb[ch + 1];
    }
    float s = dv[0].x + dv[0].y + dv[1].x + dv[1].y + dv[2].x + dv[2].y;
    float s2 = dv[0].x * dv[0].x + dv[0].y * dv[0].y + dv[1].x * dv[1].x
             + dv[1].y * dv[1].y + dv[2].x * dv[2].x + dv[2].y * dv[2].y;
    for (int off = 32; off >= 1; off >>= 1) {
        s += __shfl_xor(s, off);
        s2 += __shfl_xor(s2, off);
    }
    const float mu = s * (1.f / H_);
    const float var = s2 * (1.f / H_) - mu * mu;
    const float rs = rsqrtf(var + EPS_);
    const int bpo = (row >> 9) * APAD + (row & (L_ - 1)) + 1;   // padded row
    const long po = (long)bpo * H_;
#pragma unroll
    for (int p = 0; p < 3; ++p) {
        const int ch = 2 * (lane + 64 * p);
        float r0 = fmaxf((dv[p].x - mu) * rs * g[ch] + bt[ch], 0.f);
        float r1 = fmaxf((dv[p].y - mu) * rs * g[ch + 1] + bt[ch + 1], 0.f);
        ushort2 hv, lv;
        bf16_split(r0, hv.x, lv.x);
        bf16_split(r1, hv.y, lv.y);
        *(ushort2*)(oh + po + ch) = hv;
        *(ushort2*)(ol + po + ch) = lv;
    }
}

// ---------------------------------------------------------------------------
// Kernel 5: bias + LayerNorm + ReLU + linear + ReLU + exp -> durations.
// ---------------------------------------------------------------------------
__global__ __launch_bounds__(256) void k_fin(
        const float* __restrict__ c, const float* __restrict__ cb,
        const float* __restrict__ g, const float* __restrict__ bt,
        const float* __restrict__ lw, const float* __restrict__ lb,
        float* __restrict__ dur) {
    const int row = blockIdx.x * 4 + (threadIdx.x >> 6);
    const int lane = threadIdx.x & 63;
    const float* cr = c + (long)row * F_;
    float2 dv[3];
    dv[0] = ((const float2*)cr)[lane];
    dv[1] = ((const float2*)cr)[lane + 64];
    dv[2] = ((const float2*)cr)[lane + 128];
#pragma unroll
    for (int p = 0; p < 3; ++p) {
        const int ch = 2 * (lane + 64 * p);
        dv[p].x += cb[ch];
        dv[p].y += cb[ch + 1];
    }
    float s = dv[0].x + dv[0].y + dv[1].x + dv[1].y + dv[2].x + dv[2].y;
    float s2 = dv[0].x * dv[0].x + dv[0].y * dv[0].y + dv[1].x * dv[1].x
             + dv[1].y * dv[1].y + dv[2].x * dv[2].x + dv[2].y * dv[2].y;
    for (int off = 32; off >= 1; off >>= 1) {
        s += __shfl_xor(s, off);
        s2 += __shfl_xor(s2, off);
    }
    const float mu = s * (1.f / F_);
    const float var = s2 * (1.f / F_) - mu * mu;
    const float rs = rsqrtf(var + EPS_);
    float dot = 0.f;
#pragma unroll
    for (int p = 0; p < 3; ++p) {
        const int ch = 2 * (lane + 64 * p);
        float r0 = fmaxf((dv[p].x - mu) * rs * g[ch] + bt[ch], 0.f);
        float r1 = fmaxf((dv[p].y - mu) * rs * g[ch + 1] + bt[ch + 1], 0.f);
        dot += r0 * lw[ch] + r1 * lw[ch + 1];
    }
    for (int off = 32; off >= 1; off >>= 1) dot += __shfl_xor(dot, off);
    if (lane == 0) dur[row] = expf(fmaxf(dot + lb[0], 0.f));
}

// ---------------------------------------------------------------------------
// Kernel 6: length-regulate gather (memory bound, unchanged).
// ---------------------------------------------------------------------------
__global__ void k_gather(const float4* __restrict__ x, const int* __restrict__ idx,
                         float4* __restrict__ out) {
    const int F4 = F_ / 4;                        // 96
    const int total = B_ * MAX_OUT_ * F4;
    for (int i = blockIdx.x * blockDim.x + threadIdx.x; i < total;
         i += gridDim.x * blockDim.x) {
        int row = i / F4;
        int f4 = i - row * F4;
        int t = row % MAX_OUT_;
        int b = row / MAX_OUT_;
        int id = idx[b * MAX_OUT_ + t];
        float4 v = make_float4(0.f, 0.f, 0.f, 0.f);
        if (id >= 0) v = x[((long)b * L_ + id) * F4 + f4];
        out[i] = v;
    }
}

// ---------------------------------------------------------------------------
extern "C" void kernel_launch(void* const* d_in, const int* in_sizes, int n_in,
                              void* d_out, int out_size, void* d_ws, size_t ws_size,
                              hipStream_t stream) {
    const float* input   = (const float*)d_in[0];
    const int*   target  = (const int*)d_in[1];
    const float* conv1_w = (const float*)d_in[2];
    const float* conv1_b = (const float*)d_in[3];
    const float* ln1_g   = (const float*)d_in[4];
    const float* ln1_b   = (const float*)d_in[5];
    const float* conv2_w = (const float*)d_in[6];
    const float* conv2_b = (const float*)d_in[7];
    const float* ln2_g   = (const float*)d_in[8];
    const float* ln2_b   = (const float*)d_in[9];
    const float* lin_w   = (const float*)d_in[10];
    const float* lin_b   = (const float*)d_in[11];

    float* out0 = (float*)d_out;                                  // [B, 4096, F]
    float* dur  = out0 + (size_t)B_ * MAX_OUT_ * F_;              // [B, L]
    float* c    = out0;   // raw conv outputs scratched in out0 (overwritten by gather)

    // workspace: idx 256KB + padded x/h1 planes 12.63MB + weight planes 3.54MB
    char* ws = (char*)d_ws;
    int* idx = (int*)ws;                                          // 262144 B
    unsigned short* xh  = (unsigned short*)(ws + 262144);
    unsigned short* xl  = xh + NXP;
    unsigned short* w1h = xl + NXP;
    unsigned short* w1l = w1h + NW;
    unsigned short* w2h = w1l + NW;
    unsigned short* w2l = w2h + NW;

    hipLaunchKernelGGL(k_scan_idx, dim3(B_), dim3(L_), 0, stream, target, idx);
    hipLaunchKernelGGL(k_prep, dim3(2048), dim3(256), 0, stream,
                       input, conv1_w, conv2_w, xh, xl, w1h, w1l, w2h, w2l);
    // conv1: raw output into out0 scratch
    hipLaunchKernelGGL(k_gemm, dim3(M_TOTAL / 64, H_ / 64), dim3(256), 0, stream,
                       xh, xl, w1h, w1l, c);
    // bias+LN+ReLU, re-split into the (now dead) padded x planes
    hipLaunchKernelGGL(k_lnrelu, dim3(M_TOTAL / 4), dim3(256), 0, stream,
                       c, conv1_b, ln1_g, ln1_b, xh, xl);
    // conv2: raw output into out0 scratch
    hipLaunchKernelGGL(k_gemm, dim3(M_TOTAL / 64, H_ / 64), dim3(256), 0, stream,
                       xh, xl, w2h, w2l, c);
    // bias+LN+ReLU+linear+ReLU+exp -> durations
    hipLaunchKernelGGL(k_fin, dim3(M_TOTAL / 4), dim3(256), 0, stream,
                       c, conv2_b, ln2_g, ln2_b, lin_w, lin_b, dur);
    // finally overwrite out0 with the gather
    hipLaunchKernelGGL(k_gather, dim3(4096), dim3(256), 0, stream,
                       (const float4*)input, idx, (float4*)out0);
}